// Round 1
// baseline (16987.062 us; speedup 1.0000x reference)
//
#include <hip/hip_runtime.h>
#include <math.h>
#include <stddef.h>

#define E 1024
#define NH 16
#define DH 64
#define HID 4096
#define NLAYER 6
#define VV 32000
#define BB 4
#define SS 512
#define TT 512
#define MROWS (BB * SS)   // 2048 rows for both encoder and decoder streams

// ---------------------------------------------------------------------------
// Embedding + sinusoidal positional encoding
// out[row, e] = emb[tok[row], e] * scale + pe(pos, e),  pos = row % seqlen
// ---------------------------------------------------------------------------
__global__ __launch_bounds__(256) void embed_kernel(const int* __restrict__ tok,
                                                    const float* __restrict__ emb,
                                                    float* __restrict__ out,
                                                    int seqlen, float scale) {
    int row = blockIdx.x;
    int pos = row % seqlen;
    int t = tok[row];
    const float* erow = emb + (size_t)t * E;
    float* orow = out + (size_t)row * E;
    for (int e = threadIdx.x; e < E; e += blockDim.x) {
        int half = e >> 1;
        float freq = expf((float)(2 * half) * (-9.210340371976184f / (float)E)); // -ln(10000)/E
        float ang = (float)pos * freq;
        float pe = (e & 1) ? cosf(ang) : sinf(ang);
        orow[e] = erow[e] * scale + pe;
    }
}

// ---------------------------------------------------------------------------
// Row LayerNorm over E=1024, one block (256 thr) per row, 4 elems/thread
// ---------------------------------------------------------------------------
__global__ __launch_bounds__(256) void ln_kernel(const float* __restrict__ in,
                                                 const float* __restrict__ gamma,
                                                 const float* __restrict__ beta,
                                                 float* __restrict__ out) {
    int row = blockIdx.x;
    const float* xr = in + (size_t)row * E;
    float* orow = out + (size_t)row * E;
    int tid = threadIdx.x;
    float v[4];
    float s = 0.f;
#pragma unroll
    for (int i = 0; i < 4; ++i) { v[i] = xr[tid + 256 * i]; s += v[i]; }
    __shared__ float sh[4];
#pragma unroll
    for (int o = 32; o > 0; o >>= 1) s += __shfl_down(s, o);
    int wave = tid >> 6;
    if ((tid & 63) == 0) sh[wave] = s;
    __syncthreads();
    float mu = (sh[0] + sh[1] + sh[2] + sh[3]) * (1.f / E);
    float sq = 0.f;
#pragma unroll
    for (int i = 0; i < 4; ++i) { float d = v[i] - mu; sq += d * d; }
    __syncthreads();
#pragma unroll
    for (int o = 32; o > 0; o >>= 1) sq += __shfl_down(sq, o);
    if ((tid & 63) == 0) sh[wave] = sq;
    __syncthreads();
    float var = (sh[0] + sh[1] + sh[2] + sh[3]) * (1.f / E);
    float rstd = rsqrtf(var + 1e-5f);
#pragma unroll
    for (int i = 0; i < 4; ++i) {
        int c = tid + 256 * i;
        orow[c] = (v[i] - mu) * rstd * gamma[c] + beta[c];
    }
}

// ---------------------------------------------------------------------------
// fp32 GEMM: C = A(M,K) @ W(K,N) [+bias over N] [relu] [+res(M,N)]
// 128x128 tile, BK=16, 256 threads, 8x8 per thread.
// blockIdx.z batches over (A+z*strideA, W+z*strideW, C+z*strideC).
// Requires M%128==0, N%128==0, K%16==0 (true for all call sites).
// ---------------------------------------------------------------------------
#define BM 128
#define BN 128
#define BK 16

__global__ __launch_bounds__(256) void gemm_kernel(
    const float* __restrict__ A, const float* __restrict__ W,
    const float* __restrict__ bias, const float* __restrict__ res,
    float* __restrict__ C, int M, int N, int K, int relu,
    size_t strideA, size_t strideW, size_t strideC) {
    int z = blockIdx.z;
    A += (size_t)z * strideA;
    W += (size_t)z * strideW;
    C += (size_t)z * strideC;

    __shared__ float As[BK][BM];   // transposed: As[k][m]
    __shared__ float Bs[BK][BN];   // Bs[k][n]

    int tid = threadIdx.x;
    int tx = tid & 15, ty = tid >> 4;
    int m0 = blockIdx.y * BM;
    int n0 = blockIdx.x * BN;

    float acc[8][8];
#pragma unroll
    for (int i = 0; i < 8; ++i)
#pragma unroll
        for (int j = 0; j < 8; ++j) acc[i][j] = 0.f;

    int arow = tid >> 2;   // 0..63
    int akv = tid & 3;     // which float4 of 16 cols
    int bn4 = tid & 31;    // 0..31 float4 per B row
    int bk = tid >> 5;     // 0..7

    for (int k0 = 0; k0 < K; k0 += BK) {
        float4 a0 = *(const float4*)&A[(size_t)(m0 + arow) * K + k0 + akv * 4];
        float4 a1 = *(const float4*)&A[(size_t)(m0 + arow + 64) * K + k0 + akv * 4];
        float4 b0 = *(const float4*)&W[(size_t)(k0 + bk) * N + n0 + bn4 * 4];
        float4 b1 = *(const float4*)&W[(size_t)(k0 + bk + 8) * N + n0 + bn4 * 4];
        __syncthreads();
        As[akv * 4 + 0][arow] = a0.x;
        As[akv * 4 + 1][arow] = a0.y;
        As[akv * 4 + 2][arow] = a0.z;
        As[akv * 4 + 3][arow] = a0.w;
        As[akv * 4 + 0][arow + 64] = a1.x;
        As[akv * 4 + 1][arow + 64] = a1.y;
        As[akv * 4 + 2][arow + 64] = a1.z;
        As[akv * 4 + 3][arow + 64] = a1.w;
        *(float4*)&Bs[bk][bn4 * 4] = b0;
        *(float4*)&Bs[bk + 8][bn4 * 4] = b1;
        __syncthreads();
#pragma unroll
        for (int kk = 0; kk < BK; ++kk) {
            float4 av0 = *(const float4*)&As[kk][ty * 4];
            float4 av1 = *(const float4*)&As[kk][64 + ty * 4];
            float4 bv0 = *(const float4*)&Bs[kk][tx * 4];
            float4 bv1 = *(const float4*)&Bs[kk][64 + tx * 4];
            float am[8] = {av0.x, av0.y, av0.z, av0.w, av1.x, av1.y, av1.z, av1.w};
            float bm[8] = {bv0.x, bv0.y, bv0.z, bv0.w, bv1.x, bv1.y, bv1.z, bv1.w};
#pragma unroll
            for (int i = 0; i < 8; ++i)
#pragma unroll
                for (int j = 0; j < 8; ++j) acc[i][j] += am[i] * bm[j];
        }
    }

#pragma unroll
    for (int i = 0; i < 8; ++i) {
        int m = m0 + ty * 4 + (i & 3) + ((i >> 2) * 64);
        size_t crow = (size_t)m * N;
#pragma unroll
        for (int half = 0; half < 2; ++half) {
            int nc = n0 + half * 64 + tx * 4;
            float tmp[4];
#pragma unroll
            for (int c = 0; c < 4; ++c) {
                float val = acc[i][half * 4 + c];
                if (bias) val += bias[nc + c];
                if (relu) val = fmaxf(val, 0.f);
                if (res) val += res[crow + nc + c];
                tmp[c] = val;
            }
            float4 o = make_float4(tmp[0], tmp[1], tmp[2], tmp[3]);
            *(float4*)&C[crow + nc] = o;
        }
    }
}

// ---------------------------------------------------------------------------
// Attention scores: Sc[bh, q, k] = dot(Q[b,q,h,:], K[b,k,h,:]) / 32  (masked)
// Q rows: b*Tq + q, cols h*64..  ;  K rows: b*Tk + k
// mode 0: enc self  (srcpad[q] && srcpad[k])
// mode 1: dec self  (q>=k && tgtpad[q])
// mode 2: cross     (tgtpad[q])          (ktok unused)
// grid (Tq/64, Tk/64, B*NH), block 256; 64x64 tile, 4x4 per thread
// ---------------------------------------------------------------------------
__global__ __launch_bounds__(256) void scores_kernel(
    const float* __restrict__ Qb, const float* __restrict__ Kb,
    const int* __restrict__ qtok, const int* __restrict__ ktok,
    float* __restrict__ Sc, int Tq, int Tk, int mode) {
    int bh = blockIdx.z;
    int b = bh >> 4;
    int h = bh & 15;
    int q0 = blockIdx.x * 64;
    int k0 = blockIdx.y * 64;
    __shared__ float Qs[64][68];
    __shared__ float Ks[64][68];
    int tid = threadIdx.x;
    int f = tid & 15, r0 = tid >> 4;
#pragma unroll
    for (int it = 0; it < 4; ++it) {
        int rr = r0 + it * 16;
        *(float4*)&Qs[rr][f * 4] =
            *(const float4*)&Qb[(size_t)(b * Tq + q0 + rr) * E + h * 64 + f * 4];
        *(float4*)&Ks[rr][f * 4] =
            *(const float4*)&Kb[(size_t)(b * Tk + k0 + rr) * E + h * 64 + f * 4];
    }
    __syncthreads();
    int tx = tid & 15, ty = tid >> 4;
    float acc[4][4];
#pragma unroll
    for (int i = 0; i < 4; ++i)
#pragma unroll
        for (int j = 0; j < 4; ++j) acc[i][j] = 0.f;
#pragma unroll 4
    for (int d4 = 0; d4 < 16; ++d4) {
        float4 qa[4], kb[4];
#pragma unroll
        for (int i = 0; i < 4; ++i) qa[i] = *(const float4*)&Qs[ty * 4 + i][d4 * 4];
#pragma unroll
        for (int j = 0; j < 4; ++j) kb[j] = *(const float4*)&Ks[tx * 4 + j][d4 * 4];
#pragma unroll
        for (int i = 0; i < 4; ++i)
#pragma unroll
            for (int j = 0; j < 4; ++j)
                acc[i][j] += qa[i].x * kb[j].x + qa[i].y * kb[j].y +
                             qa[i].z * kb[j].z + qa[i].w * kb[j].w;
    }
    const float scale = 1.0f / 32.0f;  // 1/sqrt(E)
#pragma unroll
    for (int i = 0; i < 4; ++i) {
        int q = q0 + ty * 4 + i;
        bool qv = qtok[b * Tq + q] != 0;
        float tmp[4];
#pragma unroll
        for (int j = 0; j < 4; ++j) {
            int k = k0 + tx * 4 + j;
            bool ok;
            if (mode == 0)      ok = qv && (ktok[b * Tk + k] != 0);
            else if (mode == 1) ok = qv && (q >= k);
            else                ok = qv;
            tmp[j] = ok ? acc[i][j] * scale : -10000.0f;
        }
        float4 o = make_float4(tmp[0], tmp[1], tmp[2], tmp[3]);
        *(float4*)&Sc[((size_t)bh * Tq + q) * Tk + k0 + tx * 4] = o;
    }
}

// ---------------------------------------------------------------------------
// Row softmax over Tk=512, one block per row (B*NH*Tq rows), in place
// ---------------------------------------------------------------------------
__global__ __launch_bounds__(256) void softmax_kernel(float* __restrict__ Sc, int Tk) {
    size_t row = blockIdx.x;
    float* p = Sc + row * (size_t)Tk;
    int tid = threadIdx.x;
    float v0 = p[tid], v1 = p[tid + 256];
    float m = fmaxf(v0, v1);
    __shared__ float sh[4];
#pragma unroll
    for (int o = 32; o > 0; o >>= 1) m = fmaxf(m, __shfl_down(m, o));
    int wave = tid >> 6;
    if ((tid & 63) == 0) sh[wave] = m;
    __syncthreads();
    m = fmaxf(fmaxf(sh[0], sh[1]), fmaxf(sh[2], sh[3]));
    float e0 = __expf(v0 - m), e1 = __expf(v1 - m);
    float s = e0 + e1;
    __syncthreads();
#pragma unroll
    for (int o = 32; o > 0; o >>= 1) s += __shfl_down(s, o);
    if ((tid & 63) == 0) sh[wave] = s;
    __syncthreads();
    float inv = 1.f / (sh[0] + sh[1] + sh[2] + sh[3]);
    p[tid] = e0 * inv;
    p[tid + 256] = e1 * inv;
}

// ---------------------------------------------------------------------------
// ctx: out[b*Tq+q, h*64+d] = res[same] + sum_k P[bh,q,k] * V[b*Tk+k, h*64+d]
// grid (Tq/64, NH, B), block 256; 64(q) x 64(d) tile, 4x4 per thread
// ---------------------------------------------------------------------------
__global__ __launch_bounds__(256) void ctx_kernel(
    const float* __restrict__ P, const float* __restrict__ Vb,
    const float* __restrict__ res, float* __restrict__ out,
    int Tq, int Tk) {
    int b = blockIdx.z, h = blockIdx.y;
    int q0 = blockIdx.x * 64;
    int bh = b * NH + h;
    __shared__ float Ps[64][68];  // transposed: Ps[k][q]
    __shared__ float Vs[64][68];  // Vs[k][d]
    int tid = threadIdx.x;
    int f = tid & 15, r0 = tid >> 4;
    int tx = tid & 15, ty = tid >> 4;
    float acc[4][4];
#pragma unroll
    for (int i = 0; i < 4; ++i)
#pragma unroll
        for (int j = 0; j < 4; ++j) acc[i][j] = 0.f;

    for (int kc = 0; kc < Tk; kc += 64) {
        __syncthreads();
#pragma unroll
        for (int it = 0; it < 4; ++it) {
            int rr = r0 + it * 16;
            float4 pv = *(const float4*)&P[((size_t)bh * Tq + q0 + rr) * Tk + kc + f * 4];
            Ps[f * 4 + 0][rr] = pv.x;
            Ps[f * 4 + 1][rr] = pv.y;
            Ps[f * 4 + 2][rr] = pv.z;
            Ps[f * 4 + 3][rr] = pv.w;
            *(float4*)&Vs[rr][f * 4] =
                *(const float4*)&Vb[(size_t)(b * Tk + kc + rr) * E + h * 64 + f * 4];
        }
        __syncthreads();
#pragma unroll
        for (int kk = 0; kk < 64; ++kk) {
            float4 pa = *(const float4*)&Ps[kk][ty * 4];
            float4 vb = *(const float4*)&Vs[kk][tx * 4];
            float am[4] = {pa.x, pa.y, pa.z, pa.w};
            float bm[4] = {vb.x, vb.y, vb.z, vb.w};
#pragma unroll
            for (int i = 0; i < 4; ++i)
#pragma unroll
                for (int j = 0; j < 4; ++j) acc[i][j] += am[i] * bm[j];
        }
    }
#pragma unroll
    for (int i = 0; i < 4; ++i) {
        int q = q0 + ty * 4 + i;
        size_t orow = (size_t)(b * Tq + q) * E + h * 64;
        float tmp[4];
#pragma unroll
        for (int j = 0; j < 4; ++j) tmp[j] = res[orow + tx * 4 + j] + acc[i][j];
        float4 o = make_float4(tmp[0], tmp[1], tmp[2], tmp[3]);
        *(float4*)&out[orow + tx * 4] = o;
    }
}

// ---------------------------------------------------------------------------
extern "C" void kernel_launch(void* const* d_in, const int* in_sizes, int n_in,
                              void* d_out, int out_size, void* d_ws, size_t ws_size,
                              hipStream_t stream) {
    const int* src = (const int*)d_in[0];
    const int* tgt = (const int*)d_in[1];
    const float* emb_enc = (const float*)d_in[2];
    const float* emb_dec = (const float*)d_in[3];
    const float* enc_qkv = (const float*)d_in[4];
    const float* enc_w1 = (const float*)d_in[5];
    const float* enc_b1 = (const float*)d_in[6];
    const float* enc_w2 = (const float*)d_in[7];
    const float* enc_b2 = (const float*)d_in[8];
    const float* enc_ln_g = (const float*)d_in[9];
    const float* enc_ln_b = (const float*)d_in[10];
    const float* dec_qkv_self = (const float*)d_in[11];
    const float* dec_qkv_cross = (const float*)d_in[12];
    const float* dec_w1 = (const float*)d_in[13];
    const float* dec_b1 = (const float*)d_in[14];
    const float* dec_w2 = (const float*)d_in[15];
    const float* dec_b2 = (const float*)d_in[16];
    const float* dec_ln_g = (const float*)d_in[17];
    const float* dec_ln_b = (const float*)d_in[18];
    const float* fin_ln_g = (const float*)d_in[19];
    const float* fin_ln_b = (const float*)d_in[20];
    const float* out_w = (const float*)d_in[21];
    const float* out_b = (const float*)d_in[22];
    float* out = (float*)d_out;

    const size_t BSE = (size_t)BB * SS * E;        // 2,097,152 floats
    const size_t BSH = (size_t)BB * SS * HID;      // 8,388,608
    const size_t SCN = (size_t)BB * NH * SS * TT;  // 16,777,216

    float* ws = (float*)d_ws;
    float* x = ws;            // encoder stream / enc_out
    float* y = x + BSE;       // decoder stream
    float* n = y + BSE;       // layernorm output (residual source)
    float* a = n + BSE;       // attention output + residual
    float* q = a + BSE;
    float* k = q + BSE;
    float* v = k + BSE;
    float* big = v + BSE;     // shared by FFN hidden (8M) and scores (16M) — never live together
    float* h = big;
    float* sc = big;
    // total: 7*BSE + max(BSH,SCN) = 31.4M floats = ~126 MB of ws

    dim3 blk(256);
    embed_kernel<<<BB * SS, blk, 0, stream>>>(src, emb_enc, x, SS, 32.0f);
    embed_kernel<<<BB * TT, blk, 0, stream>>>(tgt, emb_dec, y, TT, 1.0f);

    dim3 gQKV(E / BN, MROWS / BM, 3);
    dim3 gQ(E / BN, MROWS / BM, 1);
    dim3 gKV(E / BN, MROWS / BM, 2);
    dim3 gFF1(HID / BN, MROWS / BM, 1);
    dim3 gFF2(E / BN, MROWS / BM, 1);
    dim3 gOut(VV / BN, MROWS / BM, 1);
    dim3 gSc(SS / 64, SS / 64, BB * NH);
    dim3 gCx(SS / 64, NH, BB);

    // ---------------- encoder ----------------
    for (int i = 0; i < NLAYER; ++i) {
        const float* g = enc_ln_g + i * E;
        const float* be = enc_ln_b + i * E;
        const float* wqkv = enc_qkv + (size_t)i * 3 * E * E;
        ln_kernel<<<MROWS, blk, 0, stream>>>(x, g, be, n);
        gemm_kernel<<<gQKV, blk, 0, stream>>>(n, wqkv, nullptr, nullptr, q,
                                              MROWS, E, E, 0, 0, (size_t)E * E, BSE);
        scores_kernel<<<gSc, blk, 0, stream>>>(q, k, src, src, sc, SS, SS, 0);
        softmax_kernel<<<BB * NH * SS, blk, 0, stream>>>(sc, SS);
        ctx_kernel<<<gCx, blk, 0, stream>>>(sc, v, n, a, SS, SS);
        ln_kernel<<<MROWS, blk, 0, stream>>>(a, g, be, n);
        gemm_kernel<<<gFF1, blk, 0, stream>>>(n, enc_w1 + (size_t)i * E * HID,
                                              enc_b1 + i * HID, nullptr, h,
                                              MROWS, HID, E, 1, 0, 0, 0);
        gemm_kernel<<<gFF2, blk, 0, stream>>>(h, enc_w2 + (size_t)i * HID * E,
                                              enc_b2 + i * E, n, x,
                                              MROWS, E, HID, 0, 0, 0, 0);
    }
    // ---------------- decoder ----------------
    for (int i = 0; i < NLAYER; ++i) {
        const float* g = dec_ln_g + i * E;
        const float* be = dec_ln_b + i * E;
        const float* wself = dec_qkv_self + (size_t)i * 3 * E * E;
        const float* wcross = dec_qkv_cross + (size_t)i * 3 * E * E;
        // self-attention
        ln_kernel<<<MROWS, blk, 0, stream>>>(y, g, be, n);
        gemm_kernel<<<gQKV, blk, 0, stream>>>(n, wself, nullptr, nullptr, q,
                                              MROWS, E, E, 0, 0, (size_t)E * E, BSE);
        scores_kernel<<<gSc, blk, 0, stream>>>(q, k, tgt, tgt, sc, TT, TT, 1);
        softmax_kernel<<<BB * NH * TT, blk, 0, stream>>>(sc, TT);
        ctx_kernel<<<gCx, blk, 0, stream>>>(sc, v, n, a, TT, TT);
        ln_kernel<<<MROWS, blk, 0, stream>>>(a, g, be, n);
        // cross-attention: Q from n, K/V from enc_out (x)
        gemm_kernel<<<gQ, blk, 0, stream>>>(n, wcross, nullptr, nullptr, q,
                                            MROWS, E, E, 0, 0, 0, 0);
        gemm_kernel<<<gKV, blk, 0, stream>>>(x, wcross + (size_t)E * E, nullptr, nullptr, k,
                                             MROWS, E, E, 0, 0, (size_t)E * E, BSE);
        scores_kernel<<<gSc, blk, 0, stream>>>(q, k, tgt, nullptr, sc, TT, SS, 2);
        softmax_kernel<<<BB * NH * TT, blk, 0, stream>>>(sc, SS);
        ctx_kernel<<<gCx, blk, 0, stream>>>(sc, v, n, a, TT, SS);
        ln_kernel<<<MROWS, blk, 0, stream>>>(a, g, be, n);
        // FFN
        gemm_kernel<<<gFF1, blk, 0, stream>>>(n, dec_w1 + (size_t)i * E * HID,
                                              dec_b1 + i * HID, nullptr, h,
                                              MROWS, HID, E, 1, 0, 0, 0);
        gemm_kernel<<<gFF2, blk, 0, stream>>>(h, dec_w2 + (size_t)i * HID * E,
                                              dec_b2 + i * E, n, y,
                                              MROWS, E, HID, 0, 0, 0, 0);
    }
    // ---------------- final LN + logits ----------------
    ln_kernel<<<MROWS, blk, 0, stream>>>(y, fin_ln_g, fin_ln_b, n);
    gemm_kernel<<<gOut, blk, 0, stream>>>(n, out_w, out_b, nullptr, out,
                                          MROWS, VV, E, 0, 0, 0, 0);
}